// Round 6
// baseline (236.783 us; speedup 1.0000x reference)
//
#include <hip/hip_runtime.h>

#define BB    16384
#define NF    24
#define CARDN 10000
#define DD    16
#define NI    276      // 24*23/2
#define H1N   128
#define H2N   64
#define SB    8        // samples per block/tile
#define PSTR  9        // pairsT [p][s] stride (8+1)
#define HSTR  9        // h1T [c][s] stride
#define NPROD 448      // producer threads = 7 waves; wave 7 = consumer
#define NPAIR (SB * NI)   // 2208

// ---------------------------------------------------------------------------
// R6: producer/consumer wave specialization.
//  - 7 producer waves: barrier-free (sample,pair) gather+dot (R5-proven
//    pattern) -> pairsT LDS, then atomicAdd(done) and EXIT (frees wave slots
//    so the next block's producers launch while our consumer MLPs).
//  - 1 consumer wave: prefetches lin-term gathers, spins on `done`, then runs
//    the full f32 MLP intra-wave (no barriers; lgkmcnt orders LDS), h2 in
//    registers, shuffle-reduced output.
//  - grid 2048 > ~1024 resident -> staggered generations: gather runs
//    continuously while consumers of finished blocks MLP "for free".
// ---------------------------------------------------------------------------
__global__ __launch_bounds__(512, 8) void fanfm_pc_kernel(
    const int* __restrict__ x, const float* __restrict__ E,
    const float* __restrict__ Wlin, const float* __restrict__ blin,
    const float* __restrict__ W1, const float* __restrict__ b1,
    const float* __restrict__ W2, const float* __restrict__ b2,
    const float* __restrict__ W3, const float* __restrict__ b3,
    float* __restrict__ out)
{
    __shared__ float pairsT[NI * PSTR];   //  9936 B
    __shared__ float h1T[H1N * HSTR];     //  4608 B
    __shared__ int   xs[SB * NF];         //   768 B
    __shared__ int   pi_tab[NI];          //  1104 B
    __shared__ int   pj_tab[NI];          //  1104 B
    __shared__ int   done;

    const int tid = threadIdx.x;
    const int b0  = blockIdx.x * SB;

    // --- init (all 512 threads present; single barrier in whole kernel) ---
    if (tid == 0) done = 0;
    for (int idx = tid; idx < SB * NF; idx += 512) xs[idx] = x[b0 * NF + idx];
    if (tid < NI) {
        int i = 0, rem = tid, cnt = NF - 1;
        while (rem >= cnt) { rem -= cnt; --cnt; ++i; }
        pi_tab[tid] = i;
        pj_tab[tid] = i + 1 + rem;
    }
    __syncthreads();

    if (tid < NPROD) {
        // ------------------ producers: 2208 pair-dots / 448 threads -------
        #pragma unroll 2
        for (int k = 0; k < 5; ++k) {
            int idx = tid + k * NPROD;
            if (idx < NPAIR) {
                int s = idx / NI;
                int p = idx - s * NI;
                int i = pi_tab[p];
                int j = pj_tab[p];
                int xi = xs[s * NF + i];
                int xj = xs[s * NF + j];
                const float4* a = (const float4*)(E + ((size_t)i * CARDN + xi) * (NF * DD) + j * DD);
                const float4* c = (const float4*)(E + ((size_t)j * CARDN + xj) * (NF * DD) + i * DD);
                float4 a0 = a[0], a1 = a[1], a2 = a[2], a3 = a[3];
                float4 c0 = c[0], c1 = c[1], c2 = c[2], c3 = c[3];
                float d =
                    a0.x*c0.x + a0.y*c0.y + a0.z*c0.z + a0.w*c0.w +
                    a1.x*c1.x + a1.y*c1.y + a1.z*c1.z + a1.w*c1.w +
                    a2.x*c2.x + a2.y*c2.y + a2.z*c2.z + a2.w*c2.w +
                    a3.x*c3.x + a3.y*c3.y + a3.z*c3.z + a3.w*c3.w;
                pairsT[p * PSTR + s] = d;
            }
        }
        __threadfence_block();
        atomicAdd(&done, 1);
        // producer waves retire here -> wave slots free for next block
    } else {
        // ------------------ consumer: 1 wave, full MLP ---------------------
        const int ct = tid - NPROD;   // 0..63
        const int s  = ct >> 3;       // 0..7  sample
        const int cg = ct & 7;        // 0..7  column group

        // linear-term partials (3 fields each) issued before the spin
        float lpart = 0.f;
        #pragma unroll
        for (int f = cg * 3; f < cg * 3 + 3; ++f)
            lpart += Wlin[f * CARDN + xs[s * NF + f]];

        while (atomicAdd(&done, 0) < NPROD) __builtin_amdgcn_s_sleep(2);

        // GEMM1: h1[s][c] for c in [cg*16, cg*16+16)
        float acc[16];
        #pragma unroll
        for (int c = 0; c < 16; ++c) acc[c] = 0.f;
        for (int p = 0; p < NI; ++p) {
            float pr = pairsT[p * PSTR + s];
            const float4* wr = (const float4*)(W1 + p * H1N + cg * 16);
            float4 w0 = wr[0], w1 = wr[1], w2 = wr[2], w3 = wr[3];
            acc[0]  = fmaf(pr, w0.x, acc[0]);  acc[1]  = fmaf(pr, w0.y, acc[1]);
            acc[2]  = fmaf(pr, w0.z, acc[2]);  acc[3]  = fmaf(pr, w0.w, acc[3]);
            acc[4]  = fmaf(pr, w1.x, acc[4]);  acc[5]  = fmaf(pr, w1.y, acc[5]);
            acc[6]  = fmaf(pr, w1.z, acc[6]);  acc[7]  = fmaf(pr, w1.w, acc[7]);
            acc[8]  = fmaf(pr, w2.x, acc[8]);  acc[9]  = fmaf(pr, w2.y, acc[9]);
            acc[10] = fmaf(pr, w2.z, acc[10]); acc[11] = fmaf(pr, w2.w, acc[11]);
            acc[12] = fmaf(pr, w3.x, acc[12]); acc[13] = fmaf(pr, w3.y, acc[13]);
            acc[14] = fmaf(pr, w3.z, acc[14]); acc[15] = fmaf(pr, w3.w, acc[15]);
        }
        {
            const float4* br = (const float4*)(b1 + cg * 16);
            float4 bb0 = br[0], bb1 = br[1], bb2 = br[2], bb3 = br[3];
            const float bbv[16] = {bb0.x,bb0.y,bb0.z,bb0.w, bb1.x,bb1.y,bb1.z,bb1.w,
                                   bb2.x,bb2.y,bb2.z,bb2.w, bb3.x,bb3.y,bb3.z,bb3.w};
            #pragma unroll
            for (int c = 0; c < 16; ++c)
                h1T[(cg * 16 + c) * HSTR + s] = fmaxf(acc[c] + bbv[c], 0.f);
        }

        // GEMM2: h2[s][c] for c in [cg*8, cg*8+8), kept in registers
        float acc2[8];
        #pragma unroll
        for (int c = 0; c < 8; ++c) acc2[c] = 0.f;
        for (int p = 0; p < H1N; ++p) {
            float pr = h1T[p * HSTR + s];
            const float4* wr = (const float4*)(W2 + p * H2N + cg * 8);
            float4 w0 = wr[0], w1 = wr[1];
            acc2[0] = fmaf(pr, w0.x, acc2[0]); acc2[1] = fmaf(pr, w0.y, acc2[1]);
            acc2[2] = fmaf(pr, w0.z, acc2[2]); acc2[3] = fmaf(pr, w0.w, acc2[3]);
            acc2[4] = fmaf(pr, w1.x, acc2[4]); acc2[5] = fmaf(pr, w1.y, acc2[5]);
            acc2[6] = fmaf(pr, w1.z, acc2[6]); acc2[7] = fmaf(pr, w1.w, acc2[7]);
        }

        // GEMM3 partial + linear partial, shuffle reduce over the 8 cg lanes
        float r = lpart;
        {
            const float4* br = (const float4*)(b2 + cg * 8);
            const float4* wr = (const float4*)(W3 + cg * 8);
            float4 bb0 = br[0], bb1 = br[1];
            float4 w30 = wr[0], w31 = wr[1];
            r += fmaxf(acc2[0] + bb0.x, 0.f) * w30.x;
            r += fmaxf(acc2[1] + bb0.y, 0.f) * w30.y;
            r += fmaxf(acc2[2] + bb0.z, 0.f) * w30.z;
            r += fmaxf(acc2[3] + bb0.w, 0.f) * w30.w;
            r += fmaxf(acc2[4] + bb1.x, 0.f) * w31.x;
            r += fmaxf(acc2[5] + bb1.y, 0.f) * w31.y;
            r += fmaxf(acc2[6] + bb1.z, 0.f) * w31.z;
            r += fmaxf(acc2[7] + bb1.w, 0.f) * w31.w;
        }
        r += __shfl_xor(r, 1);
        r += __shfl_xor(r, 2);
        r += __shfl_xor(r, 4);
        if (cg == 0) out[b0 + s] = r + blin[0] + b3[0];
    }
}

extern "C" void kernel_launch(void* const* d_in, const int* in_sizes, int n_in,
                              void* d_out, int out_size, void* d_ws, size_t ws_size,
                              hipStream_t stream) {
    const int*   x    = (const int*)  d_in[0];
    const float* E    = (const float*)d_in[1];
    const float* Wlin = (const float*)d_in[2];
    const float* blin = (const float*)d_in[3];
    const float* W1   = (const float*)d_in[4];
    const float* b1   = (const float*)d_in[5];
    const float* W2   = (const float*)d_in[6];
    const float* b2   = (const float*)d_in[7];
    const float* W3   = (const float*)d_in[8];
    const float* b3   = (const float*)d_in[9];
    float* out = (float*)d_out;

    fanfm_pc_kernel<<<BB / SB, 512, 0, stream>>>(
        x, E, Wlin, blin, W1, b1, W2, b2, W3, b3, out);
}